// Round 5
// baseline (118.155 us; speedup 1.0000x reference)
//
#include <hip/hip_runtime.h>
#include <cstdint>

#define T_DIM 1024
#define O_DIM 512
#define D_DIM 256
#define H_DIM 512
#define H2_DIM 256   // packed h-pairs

typedef _Float16 f16x2 __attribute__((ext_vector_type(2)));
typedef _Float16 f16x8 __attribute__((ext_vector_type(8)));
typedef float f32x4 __attribute__((ext_vector_type(4)));

__device__ __forceinline__ float fdot2f(f16x2 a, f16x2 b, float c) {
#if __has_builtin(__builtin_amdgcn_fdot2)
    return __builtin_amdgcn_fdot2(a, b, c, false);
#else
    return fmaf((float)a.x, (float)b.x, fmaf((float)a.y, (float)b.y, c));
#endif
}

__device__ __forceinline__ uint32_t pack2(float a, float b) {
    f16x2 p;
    p.x = (_Float16)a;
    p.y = (_Float16)b;
    return __builtin_bit_cast(uint32_t, p);
}

struct u4 { uint32_t x, y, z, w; };

// ---------------- Kernel A: MFMA f16 dual GEMM -> packed transposed ws -----
// D'[n][m] = sum_k W1[k][n]*Amat[m][k] (+b1 for ht), stored as
// outT2[h2=n/2][m] = f16pair(n, n+1).  C/D layout: col(lane&15)=m,
// row(quad*4+reg)=n -> 4 regs = 4 consecutive n = two h-pairs in-lane.
#define GA_PAD 20   // uint32 (f16-pair) row stride: 16 kp + 4 pad (2-way only)

__global__ __launch_bounds__(256) void gemm_a(
    const float* __restrict__ z_t, const float* __restrict__ z_o,
    const float* __restrict__ W1, const float* __restrict__ b1,
    uint32_t* __restrict__ htT2, uint32_t* __restrict__ hoT2)
{
    const int bm = blockIdx.x;
    const int bn = blockIdx.y;
    const bool is_o = bm >= (T_DIM / 64);
    const float* Amat = is_o ? z_o : z_t;
    const int m0 = (is_o ? bm - T_DIM / 64 : bm) * 64;
    const int n0 = bn * 64;
    const int krow0 = is_o ? D_DIM : 0;
    const int Mdim = is_o ? O_DIM : T_DIM;
    uint32_t* outT2 = is_o ? hoT2 : htT2;

    __shared__ __align__(16) uint32_t lds_a[64 * GA_PAD];  // [m][kp] f16 pairs
    __shared__ __align__(16) uint32_t lds_w[64 * GA_PAD];  // [n][kp] f16 pairs

    const int tid = threadIdx.x;
    const int lane = tid & 63;
    const int wv = tid >> 6;       // wave id 0..3 -> n-slice
    const int quad = lane >> 4;
    const int l15 = lane & 15;

    f32x4 acc[4];
#pragma unroll
    for (int i = 0; i < 4; ++i) acc[i] = (f32x4)(0.0f);

    const int a_m = tid >> 2;
    const int a_kq = (tid & 3) * 8;
    const int w_kp = tid >> 4;
    const int w_nq = (tid & 15) * 4;

    for (int k0 = 0; k0 < D_DIM; k0 += 32) {
        // stage Amat tile 64m x 32k -> lds_a[m][kp]
        {
            const float* p = &Amat[(size_t)(m0 + a_m) * D_DIM + k0 + a_kq];
            float4 v0 = *reinterpret_cast<const float4*>(p);
            float4 v1 = *reinterpret_cast<const float4*>(p + 4);
            lds_a[a_m * GA_PAD + a_kq / 2 + 0] = pack2(v0.x, v0.y);
            lds_a[a_m * GA_PAD + a_kq / 2 + 1] = pack2(v0.z, v0.w);
            lds_a[a_m * GA_PAD + a_kq / 2 + 2] = pack2(v1.x, v1.y);
            lds_a[a_m * GA_PAD + a_kq / 2 + 3] = pack2(v1.z, v1.w);
        }
        // stage W1 tile 32k x 64n transposed -> lds_w[n][kp]
        {
            const float* r0 = &W1[(size_t)(krow0 + k0 + 2 * w_kp) * H_DIM + n0 + w_nq];
            float4 a0 = *reinterpret_cast<const float4*>(r0);
            float4 a1 = *reinterpret_cast<const float4*>(r0 + H_DIM);
            lds_w[(w_nq + 0) * GA_PAD + w_kp] = pack2(a0.x, a1.x);
            lds_w[(w_nq + 1) * GA_PAD + w_kp] = pack2(a0.y, a1.y);
            lds_w[(w_nq + 2) * GA_PAD + w_kp] = pack2(a0.z, a1.z);
            lds_w[(w_nq + 3) * GA_PAD + w_kp] = pack2(a0.w, a1.w);
        }
        __syncthreads();

        u4 au;
        {
            const uint32_t* s = &lds_w[(wv * 16 + l15) * GA_PAD + quad * 4];
            au.x = s[0]; au.y = s[1]; au.z = s[2]; au.w = s[3];
        }
        f16x8 afrag = __builtin_bit_cast(f16x8, au);
#pragma unroll
        for (int mi = 0; mi < 4; ++mi) {
            u4 bu;
            const uint32_t* s = &lds_a[(mi * 16 + l15) * GA_PAD + quad * 4];
            bu.x = s[0]; bu.y = s[1]; bu.z = s[2]; bu.w = s[3];
            f16x8 bfrag = __builtin_bit_cast(f16x8, bu);
            acc[mi] = __builtin_amdgcn_mfma_f32_16x16x32_f16(afrag, bfrag,
                                                             acc[mi], 0, 0, 0);
        }
        __syncthreads();
    }

    const int nbase = n0 + wv * 16 + quad * 4;
    float b0 = 0.f, b1v = 0.f, b2v = 0.f, b3v = 0.f;
    if (!is_o) {
        b0 = b1[nbase + 0]; b1v = b1[nbase + 1];
        b2v = b1[nbase + 2]; b3v = b1[nbase + 3];
    }
#pragma unroll
    for (int mi = 0; mi < 4; ++mi) {
        const int m = m0 + mi * 16 + l15;
        outT2[(size_t)((nbase >> 1) + 0) * Mdim + m] = pack2(acc[mi][0] + b0, acc[mi][1] + b1v);
        outT2[(size_t)((nbase >> 1) + 1) * Mdim + m] = pack2(acc[mi][2] + b2v, acc[mi][3] + b3v);
    }
}

// ---------------- Kernel B: fused leaky-dot, h-split partials --------------
// part[hs][t][o] = sum_{h in chunk} W2[h] * leaky(ht[t,h]+ho[o,h])
// leaky(x) = max(x, 0.01x) computed packed: pk_add, pk_mul, pk_max, dot2.
#define R_HC 64   // h2 pairs per block (=128 h), 4 splits

__global__ __launch_bounds__(256) void reduce_b(
    const uint32_t* __restrict__ htT2, const uint32_t* __restrict__ hoT2,
    const float* __restrict__ W2, float* __restrict__ part)
{
    __shared__ __align__(16) uint32_t ht_s[R_HC * 64];  // [h2][t]
    __shared__ __align__(16) uint32_t ho_s[R_HC * 64];  // [h2][o]
    __shared__ uint32_t w2s[R_HC];

    const int tid = threadIdx.x;
    const int t0 = blockIdx.x * 64;
    const int o0 = blockIdx.y * 64;
    const int h2b = blockIdx.z * R_HC;

    if (tid < R_HC)
        w2s[tid] = pack2(W2[(h2b + tid) * 2], W2[(h2b + tid) * 2 + 1]);

#pragma unroll
    for (int r = 0; r < 4; ++r) {
        const int c = tid + r * 256;
        const int row = c >> 4;
        const int c4 = (c & 15) * 4;
        *reinterpret_cast<uint4*>(&ht_s[row * 64 + c4]) =
            *reinterpret_cast<const uint4*>(&htT2[(size_t)(h2b + row) * T_DIM + t0 + c4]);
        *reinterpret_cast<uint4*>(&ho_s[row * 64 + c4]) =
            *reinterpret_cast<const uint4*>(&hoT2[(size_t)(h2b + row) * O_DIM + o0 + c4]);
    }
    __syncthreads();

    const int tx = tid & 15;   // o dir, 4 each
    const int ty = tid >> 4;   // t dir, 4 each

    f16x2 c001;
    c001.x = (_Float16)0.01f;
    c001.y = (_Float16)0.01f;

    float acc[4][4] = {};

#pragma unroll 4
    for (int h2 = 0; h2 < R_HC; ++h2) {
        f16x2 w = __builtin_bit_cast(f16x2, w2s[h2]);
        uint4 a = *reinterpret_cast<const uint4*>(&ht_s[h2 * 64 + ty * 4]);
        uint4 b = *reinterpret_cast<const uint4*>(&ho_s[h2 * 64 + tx * 4]);
        uint32_t av[4] = {a.x, a.y, a.z, a.w};
        uint32_t bv[4] = {b.x, b.y, b.z, b.w};
#pragma unroll
        for (int i = 0; i < 4; ++i)
#pragma unroll
            for (int j = 0; j < 4; ++j) {
                f16x2 s = __builtin_bit_cast(f16x2, av[i]) +
                          __builtin_bit_cast(f16x2, bv[j]);     // v_pk_add_f16
                f16x2 s2 = s * c001;                            // v_pk_mul_f16
                f16x2 l;                                        // v_pk_max_f16
                l.x = s.x > s2.x ? s.x : s2.x;
                l.y = s.y > s2.y ? s.y : s2.y;
                acc[i][j] = fdot2f(l, w, acc[i][j]);            // v_dot2_f32_f16
            }
    }

    float* p = part + (size_t)blockIdx.z * T_DIM * O_DIM;
#pragma unroll
    for (int i = 0; i < 4; ++i) {
        float4 v = make_float4(acc[i][0], acc[i][1], acc[i][2], acc[i][3]);
        *reinterpret_cast<float4*>(
            &p[(size_t)(t0 + ty * 4 + i) * O_DIM + o0 + tx * 4]) = v;
    }
}

// ---------------- Kernel C: combine ----------------------------------------
// out = b2 + sum_hs part
__global__ __launch_bounds__(256) void combine(
    const float* __restrict__ part, const float* __restrict__ b2,
    float* __restrict__ out)
{
    const float bb = b2[0];
    const int Q = T_DIM * O_DIM / 4;
#pragma unroll
    for (int r = 0; r < 2; ++r) {
        const int idx = blockIdx.x * 512 + r * 256 + threadIdx.x;
        const float4* p = reinterpret_cast<const float4*>(part);
        float4 s0 = p[idx];
        float4 s1 = p[idx + Q];
        float4 s2 = p[idx + 2 * Q];
        float4 s3 = p[idx + 3 * Q];
        float4 o;
        o.x = bb + (s0.x + s1.x) + (s2.x + s3.x);
        o.y = bb + (s0.y + s1.y) + (s2.y + s3.y);
        o.z = bb + (s0.z + s1.z) + (s2.z + s3.z);
        o.w = bb + (s0.w + s1.w) + (s2.w + s3.w);
        reinterpret_cast<float4*>(out)[idx] = o;
    }
}

extern "C" void kernel_launch(void* const* d_in, const int* in_sizes, int n_in,
                              void* d_out, int out_size, void* d_ws, size_t ws_size,
                              hipStream_t stream) {
    const float* z_t = (const float*)d_in[0];
    const float* z_o = (const float*)d_in[1];
    const float* W1  = (const float*)d_in[2];
    const float* b1  = (const float*)d_in[3];
    const float* W2  = (const float*)d_in[4];
    const float* b2  = (const float*)d_in[5];
    float* out = (float*)d_out;

    // ws layout: htT2 1MB | hoT2 0.5MB | part 8MB @ 2MB
    char* wsb = (char*)d_ws;
    uint32_t* htT2 = (uint32_t*)(wsb);
    uint32_t* hoT2 = (uint32_t*)(wsb + (1u << 20));
    float* part    = (float*)(wsb + 0x200000);

    dim3 gridA((T_DIM + O_DIM) / 64, H_DIM / 64);       // (24, 8)
    gemm_a<<<gridA, 256, 0, stream>>>(z_t, z_o, W1, b1, htT2, hoT2);

    dim3 gridB(T_DIM / 64, O_DIM / 64, H2_DIM / R_HC);  // (16, 8, 4)
    reduce_b<<<gridB, 256, 0, stream>>>(htT2, hoT2, W2, part);

    combine<<<T_DIM * O_DIM / (4 * 512), 256, 0, stream>>>(part, b2, out);
}

// Round 6
// 100.532 us; speedup vs baseline: 1.1753x; 1.1753x over previous
//
#include <hip/hip_runtime.h>
#include <cstdint>

#define T_DIM 1024
#define O_DIM 512
#define D_DIM 256
#define H_DIM 512
#define H2_DIM 256   // packed h-pairs

typedef _Float16 f16x2 __attribute__((ext_vector_type(2)));
typedef _Float16 f16x8 __attribute__((ext_vector_type(8)));
typedef float f32x4 __attribute__((ext_vector_type(4)));

__device__ __forceinline__ uint32_t pack2(float a, float b) {
    f16x2 p;
    p.x = (_Float16)a;
    p.y = (_Float16)b;
    return __builtin_bit_cast(uint32_t, p);
}

// --- guaranteed-VOP3P packed ops (codegen was scalarizing the C++ forms) ---
__device__ __forceinline__ uint32_t pk_add(uint32_t a, uint32_t b) {
    uint32_t d;
    asm("v_pk_add_f16 %0, %1, %2" : "=v"(d) : "v"(a), "v"(b));
    return d;
}
__device__ __forceinline__ uint32_t pk_mul(uint32_t a, uint32_t b) {
    uint32_t d;
    asm("v_pk_mul_f16 %0, %1, %2" : "=v"(d) : "v"(a), "v"(b));
    return d;
}
__device__ __forceinline__ uint32_t pk_max(uint32_t a, uint32_t b) {
    uint32_t d;
    asm("v_pk_max_f16 %0, %1, %2" : "=v"(d) : "v"(a), "v"(b));
    return d;
}
__device__ __forceinline__ float dot2(uint32_t a, uint32_t b, float c) {
    float d;
    asm("v_dot2_f32_f16 %0, %1, %2, %3" : "=v"(d) : "v"(a), "v"(b), "v"(c));
    return d;
}

struct u4 { uint32_t x, y, z, w; };

// ---------------- Kernel A: MFMA f16 dual GEMM -> packed transposed ws -----
// D'[n][m] = sum_k W1[k][n]*Amat[m][k] (+b1 for ht), stored as
// outT2[h2=n/2][m] = f16pair(n, n+1).  C/D layout: col(lane&15)=m,
// row(quad*4+reg)=n -> 4 regs = 4 consecutive n = two h-pairs in-lane.
#define GA_PAD 20   // uint32 (f16-pair) row stride: 16 kp + 4 pad (2-way only)

__global__ __launch_bounds__(256) void gemm_a(
    const float* __restrict__ z_t, const float* __restrict__ z_o,
    const float* __restrict__ W1, const float* __restrict__ b1,
    uint32_t* __restrict__ htT2, uint32_t* __restrict__ hoT2)
{
    const int bm = blockIdx.x;
    const int bn = blockIdx.y;
    const bool is_o = bm >= (T_DIM / 64);
    const float* Amat = is_o ? z_o : z_t;
    const int m0 = (is_o ? bm - T_DIM / 64 : bm) * 64;
    const int n0 = bn * 64;
    const int krow0 = is_o ? D_DIM : 0;
    const int Mdim = is_o ? O_DIM : T_DIM;
    uint32_t* outT2 = is_o ? hoT2 : htT2;

    __shared__ __align__(16) uint32_t lds_a[64 * GA_PAD];  // [m][kp] f16 pairs
    __shared__ __align__(16) uint32_t lds_w[64 * GA_PAD];  // [n][kp] f16 pairs

    const int tid = threadIdx.x;
    const int lane = tid & 63;
    const int wv = tid >> 6;       // wave id 0..3 -> n-slice
    const int quad = lane >> 4;
    const int l15 = lane & 15;

    f32x4 acc[4];
#pragma unroll
    for (int i = 0; i < 4; ++i) acc[i] = (f32x4)(0.0f);

    const int a_m = tid >> 2;
    const int a_kq = (tid & 3) * 8;
    const int w_kp = tid >> 4;
    const int w_nq = (tid & 15) * 4;

    for (int k0 = 0; k0 < D_DIM; k0 += 32) {
        // stage Amat tile 64m x 32k -> lds_a[m][kp]
        {
            const float* p = &Amat[(size_t)(m0 + a_m) * D_DIM + k0 + a_kq];
            float4 v0 = *reinterpret_cast<const float4*>(p);
            float4 v1 = *reinterpret_cast<const float4*>(p + 4);
            lds_a[a_m * GA_PAD + a_kq / 2 + 0] = pack2(v0.x, v0.y);
            lds_a[a_m * GA_PAD + a_kq / 2 + 1] = pack2(v0.z, v0.w);
            lds_a[a_m * GA_PAD + a_kq / 2 + 2] = pack2(v1.x, v1.y);
            lds_a[a_m * GA_PAD + a_kq / 2 + 3] = pack2(v1.z, v1.w);
        }
        // stage W1 tile 32k x 64n transposed -> lds_w[n][kp]
        {
            const float* r0 = &W1[(size_t)(krow0 + k0 + 2 * w_kp) * H_DIM + n0 + w_nq];
            float4 a0 = *reinterpret_cast<const float4*>(r0);
            float4 a1 = *reinterpret_cast<const float4*>(r0 + H_DIM);
            lds_w[(w_nq + 0) * GA_PAD + w_kp] = pack2(a0.x, a1.x);
            lds_w[(w_nq + 1) * GA_PAD + w_kp] = pack2(a0.y, a1.y);
            lds_w[(w_nq + 2) * GA_PAD + w_kp] = pack2(a0.z, a1.z);
            lds_w[(w_nq + 3) * GA_PAD + w_kp] = pack2(a0.w, a1.w);
        }
        __syncthreads();

        u4 au;
        {
            const uint32_t* s = &lds_w[(wv * 16 + l15) * GA_PAD + quad * 4];
            au.x = s[0]; au.y = s[1]; au.z = s[2]; au.w = s[3];
        }
        f16x8 afrag = __builtin_bit_cast(f16x8, au);
#pragma unroll
        for (int mi = 0; mi < 4; ++mi) {
            u4 bu;
            const uint32_t* s = &lds_a[(mi * 16 + l15) * GA_PAD + quad * 4];
            bu.x = s[0]; bu.y = s[1]; bu.z = s[2]; bu.w = s[3];
            f16x8 bfrag = __builtin_bit_cast(f16x8, bu);
            acc[mi] = __builtin_amdgcn_mfma_f32_16x16x32_f16(afrag, bfrag,
                                                             acc[mi], 0, 0, 0);
        }
        __syncthreads();
    }

    const int nbase = n0 + wv * 16 + quad * 4;
    float b0 = 0.f, b1v = 0.f, b2v = 0.f, b3v = 0.f;
    if (!is_o) {
        b0 = b1[nbase + 0]; b1v = b1[nbase + 1];
        b2v = b1[nbase + 2]; b3v = b1[nbase + 3];
    }
#pragma unroll
    for (int mi = 0; mi < 4; ++mi) {
        const int m = m0 + mi * 16 + l15;
        outT2[(size_t)((nbase >> 1) + 0) * Mdim + m] = pack2(acc[mi][0] + b0, acc[mi][1] + b1v);
        outT2[(size_t)((nbase >> 1) + 1) * Mdim + m] = pack2(acc[mi][2] + b2v, acc[mi][3] + b3v);
    }
}

// ---------------- Kernel B: fused leaky-dot, h-split partials --------------
// part[hs][t][o] = sum_{h in chunk} W2[h] * leaky(ht[t,h]+ho[o,h])
// leaky(x) = max(x, 0.01x); inner loop pinned to 4 VOP3P insts via asm.
#define R_HC 32   // h2 pairs per block (=64 h), 8 splits -> 1024 blocks

__global__ __launch_bounds__(256) void reduce_b(
    const uint32_t* __restrict__ htT2, const uint32_t* __restrict__ hoT2,
    const float* __restrict__ W2, float* __restrict__ part)
{
    __shared__ __align__(16) uint32_t ht_s[R_HC * 64];  // [h2][t]
    __shared__ __align__(16) uint32_t ho_s[R_HC * 64];  // [h2][o]
    __shared__ uint32_t w2s[R_HC];

    const int tid = threadIdx.x;
    const int t0 = blockIdx.x * 64;
    const int o0 = blockIdx.y * 64;
    const int h2b = blockIdx.z * R_HC;

    if (tid < R_HC)
        w2s[tid] = pack2(W2[(h2b + tid) * 2], W2[(h2b + tid) * 2 + 1]);

#pragma unroll
    for (int r = 0; r < 2; ++r) {
        const int c = tid + r * 256;
        const int row = c >> 4;
        const int c4 = (c & 15) * 4;
        *reinterpret_cast<uint4*>(&ht_s[row * 64 + c4]) =
            *reinterpret_cast<const uint4*>(&htT2[(size_t)(h2b + row) * T_DIM + t0 + c4]);
        *reinterpret_cast<uint4*>(&ho_s[row * 64 + c4]) =
            *reinterpret_cast<const uint4*>(&hoT2[(size_t)(h2b + row) * O_DIM + o0 + c4]);
    }
    __syncthreads();

    const int tx = tid & 15;   // o dir, 4 each
    const int ty = tid >> 4;   // t dir, 4 each

    const uint32_t c001 = pack2(0.01f, 0.01f);   // hoisted VGPR constant

    float acc[4][4] = {};

#pragma unroll 4
    for (int h2 = 0; h2 < R_HC; ++h2) {
        const uint32_t w = w2s[h2];
        uint4 a = *reinterpret_cast<const uint4*>(&ht_s[h2 * 64 + ty * 4]);
        uint4 b = *reinterpret_cast<const uint4*>(&ho_s[h2 * 64 + tx * 4]);
        uint32_t av[4] = {a.x, a.y, a.z, a.w};
        uint32_t bv[4] = {b.x, b.y, b.z, b.w};
#pragma unroll
        for (int i = 0; i < 4; ++i)
#pragma unroll
            for (int j = 0; j < 4; ++j) {
                uint32_t s  = pk_add(av[i], bv[j]);   // v_pk_add_f16
                uint32_t s2 = pk_mul(s, c001);        // v_pk_mul_f16
                uint32_t l  = pk_max(s, s2);          // v_pk_max_f16
                acc[i][j]   = dot2(l, w, acc[i][j]);  // v_dot2_f32_f16
            }
    }

    float* p = part + (size_t)blockIdx.z * T_DIM * O_DIM;
#pragma unroll
    for (int i = 0; i < 4; ++i) {
        float4 v = make_float4(acc[i][0], acc[i][1], acc[i][2], acc[i][3]);
        *reinterpret_cast<float4*>(
            &p[(size_t)(t0 + ty * 4 + i) * O_DIM + o0 + tx * 4]) = v;
    }
}

// ---------------- Kernel C: combine ----------------------------------------
// out = b2 + sum_{hs=0..7} part[hs]
__global__ __launch_bounds__(256) void combine(
    const float* __restrict__ part, const float* __restrict__ b2,
    float* __restrict__ out)
{
    const float bb = b2[0];
    const int Q = T_DIM * O_DIM / 4;
#pragma unroll
    for (int r = 0; r < 2; ++r) {
        const int idx = blockIdx.x * 512 + r * 256 + threadIdx.x;
        const float4* p = reinterpret_cast<const float4*>(part);
        float4 s[8];
#pragma unroll
        for (int hs = 0; hs < 8; ++hs) s[hs] = p[idx + hs * Q];
        float4 o;
        o.x = bb + ((s[0].x + s[1].x) + (s[2].x + s[3].x)) +
                   ((s[4].x + s[5].x) + (s[6].x + s[7].x));
        o.y = bb + ((s[0].y + s[1].y) + (s[2].y + s[3].y)) +
                   ((s[4].y + s[5].y) + (s[6].y + s[7].y));
        o.z = bb + ((s[0].z + s[1].z) + (s[2].z + s[3].z)) +
                   ((s[4].z + s[5].z) + (s[6].z + s[7].z));
        o.w = bb + ((s[0].w + s[1].w) + (s[2].w + s[3].w)) +
                   ((s[4].w + s[5].w) + (s[6].w + s[7].w));
        reinterpret_cast<float4*>(out)[idx] = o;
    }
}

extern "C" void kernel_launch(void* const* d_in, const int* in_sizes, int n_in,
                              void* d_out, int out_size, void* d_ws, size_t ws_size,
                              hipStream_t stream) {
    const float* z_t = (const float*)d_in[0];
    const float* z_o = (const float*)d_in[1];
    const float* W1  = (const float*)d_in[2];
    const float* b1  = (const float*)d_in[3];
    const float* W2  = (const float*)d_in[4];
    const float* b2  = (const float*)d_in[5];
    float* out = (float*)d_out;

    // ws layout: htT2 1MB | hoT2 0.5MB | part 16MB @ 2MB
    char* wsb = (char*)d_ws;
    uint32_t* htT2 = (uint32_t*)(wsb);
    uint32_t* hoT2 = (uint32_t*)(wsb + (1u << 20));
    float* part    = (float*)(wsb + 0x200000);

    dim3 gridA((T_DIM + O_DIM) / 64, H_DIM / 64);       // (24, 8)
    gemm_a<<<gridA, 256, 0, stream>>>(z_t, z_o, W1, b1, htT2, hoT2);

    dim3 gridB(T_DIM / 64, O_DIM / 64, H2_DIM / R_HC);  // (16, 8, 8)
    reduce_b<<<gridB, 256, 0, stream>>>(htT2, hoT2, W2, part);

    combine<<<T_DIM * O_DIM / (4 * 512), 256, 0, stream>>>(part, b2, out);
}

// Round 7
// 95.315 us; speedup vs baseline: 1.2396x; 1.0547x over previous
//
#include <hip/hip_runtime.h>
#include <cstdint>

#define T_DIM 1024
#define O_DIM 512
#define D_DIM 256
#define H_DIM 512
#define H2_DIM 256   // packed h-pairs

typedef _Float16 f16x2 __attribute__((ext_vector_type(2)));
typedef _Float16 f16x8 __attribute__((ext_vector_type(8)));
typedef float f32x4 __attribute__((ext_vector_type(4)));

__device__ __forceinline__ uint32_t pack2(float a, float b) {
    f16x2 p;
    p.x = (_Float16)a;
    p.y = (_Float16)b;
    return __builtin_bit_cast(uint32_t, p);
}

// --- guaranteed-VOP3P packed ops (C++ half-wise forms scalarized in R5) ----
__device__ __forceinline__ uint32_t pk_add(uint32_t a, uint32_t b) {
    uint32_t d;
    asm("v_pk_add_f16 %0, %1, %2" : "=v"(d) : "v"(a), "v"(b));
    return d;
}
__device__ __forceinline__ uint32_t pk_mul(uint32_t a, uint32_t b) {
    uint32_t d;
    asm("v_pk_mul_f16 %0, %1, %2" : "=v"(d) : "v"(a), "v"(b));
    return d;
}
__device__ __forceinline__ uint32_t pk_max(uint32_t a, uint32_t b) {
    uint32_t d;
    asm("v_pk_max_f16 %0, %1, %2" : "=v"(d) : "v"(a), "v"(b));
    return d;
}
__device__ __forceinline__ float dot2(uint32_t a, uint32_t b, float c) {
    float d;
    asm("v_dot2_f32_f16 %0, %1, %2, %3" : "=v"(d) : "v"(a), "v"(b), "v"(c));
    return d;
}

struct u4 { uint32_t x, y, z, w; };

// ---------------- Kernel A: MFMA f16 dual GEMM -> packed transposed ws -----
// D'[n][m] = sum_k W1[k][n]*Amat[m][k] (+b1 for ht), stored as
// outT2[h2=n/2][m] = f16pair(n, n+1).  C/D layout: col(lane&15)=m,
// row(quad*4+reg)=n -> 4 regs = 4 consecutive n = two h-pairs in-lane.
#define GA_PAD 20   // uint32 (f16-pair) row stride: 16 kp + 4 pad (2-way only)

__global__ __launch_bounds__(256) void gemm_a(
    const float* __restrict__ z_t, const float* __restrict__ z_o,
    const float* __restrict__ W1, const float* __restrict__ b1,
    uint32_t* __restrict__ htT2, uint32_t* __restrict__ hoT2)
{
    const int bm = blockIdx.x;
    const int bn = blockIdx.y;
    const bool is_o = bm >= (T_DIM / 64);
    const float* Amat = is_o ? z_o : z_t;
    const int m0 = (is_o ? bm - T_DIM / 64 : bm) * 64;
    const int n0 = bn * 64;
    const int krow0 = is_o ? D_DIM : 0;
    const int Mdim = is_o ? O_DIM : T_DIM;
    uint32_t* outT2 = is_o ? hoT2 : htT2;

    __shared__ __align__(16) uint32_t lds_a[64 * GA_PAD];  // [m][kp] f16 pairs
    __shared__ __align__(16) uint32_t lds_w[64 * GA_PAD];  // [n][kp] f16 pairs

    const int tid = threadIdx.x;
    const int lane = tid & 63;
    const int wv = tid >> 6;       // wave id 0..3 -> n-slice
    const int quad = lane >> 4;
    const int l15 = lane & 15;

    f32x4 acc[4];
#pragma unroll
    for (int i = 0; i < 4; ++i) acc[i] = (f32x4)(0.0f);

    const int a_m = tid >> 2;
    const int a_kq = (tid & 3) * 8;
    const int w_kp = tid >> 4;
    const int w_nq = (tid & 15) * 4;

    for (int k0 = 0; k0 < D_DIM; k0 += 32) {
        // stage Amat tile 64m x 32k -> lds_a[m][kp]
        {
            const float* p = &Amat[(size_t)(m0 + a_m) * D_DIM + k0 + a_kq];
            float4 v0 = *reinterpret_cast<const float4*>(p);
            float4 v1 = *reinterpret_cast<const float4*>(p + 4);
            lds_a[a_m * GA_PAD + a_kq / 2 + 0] = pack2(v0.x, v0.y);
            lds_a[a_m * GA_PAD + a_kq / 2 + 1] = pack2(v0.z, v0.w);
            lds_a[a_m * GA_PAD + a_kq / 2 + 2] = pack2(v1.x, v1.y);
            lds_a[a_m * GA_PAD + a_kq / 2 + 3] = pack2(v1.z, v1.w);
        }
        // stage W1 tile 32k x 64n transposed -> lds_w[n][kp]
        {
            const float* r0 = &W1[(size_t)(krow0 + k0 + 2 * w_kp) * H_DIM + n0 + w_nq];
            float4 a0 = *reinterpret_cast<const float4*>(r0);
            float4 a1 = *reinterpret_cast<const float4*>(r0 + H_DIM);
            lds_w[(w_nq + 0) * GA_PAD + w_kp] = pack2(a0.x, a1.x);
            lds_w[(w_nq + 1) * GA_PAD + w_kp] = pack2(a0.y, a1.y);
            lds_w[(w_nq + 2) * GA_PAD + w_kp] = pack2(a0.z, a1.z);
            lds_w[(w_nq + 3) * GA_PAD + w_kp] = pack2(a0.w, a1.w);
        }
        __syncthreads();

        u4 au;
        {
            const uint32_t* s = &lds_w[(wv * 16 + l15) * GA_PAD + quad * 4];
            au.x = s[0]; au.y = s[1]; au.z = s[2]; au.w = s[3];
        }
        f16x8 afrag = __builtin_bit_cast(f16x8, au);
#pragma unroll
        for (int mi = 0; mi < 4; ++mi) {
            u4 bu;
            const uint32_t* s = &lds_a[(mi * 16 + l15) * GA_PAD + quad * 4];
            bu.x = s[0]; bu.y = s[1]; bu.z = s[2]; bu.w = s[3];
            f16x8 bfrag = __builtin_bit_cast(f16x8, bu);
            acc[mi] = __builtin_amdgcn_mfma_f32_16x16x32_f16(afrag, bfrag,
                                                             acc[mi], 0, 0, 0);
        }
        __syncthreads();
    }

    const int nbase = n0 + wv * 16 + quad * 4;
    float b0 = 0.f, b1v = 0.f, b2v = 0.f, b3v = 0.f;
    if (!is_o) {
        b0 = b1[nbase + 0]; b1v = b1[nbase + 1];
        b2v = b1[nbase + 2]; b3v = b1[nbase + 3];
    }
#pragma unroll
    for (int mi = 0; mi < 4; ++mi) {
        const int m = m0 + mi * 16 + l15;
        outT2[(size_t)((nbase >> 1) + 0) * Mdim + m] = pack2(acc[mi][0] + b0, acc[mi][1] + b1v);
        outT2[(size_t)((nbase >> 1) + 1) * Mdim + m] = pack2(acc[mi][2] + b2v, acc[mi][3] + b3v);
    }
}

// ---------------- Kernel B: fused leaky-dot, h-split partials --------------
// part[hs][t][o] = sum_{h in chunk} W2[h] * leaky(ht[t,h]+ho[o,h])
// leaky(x) = max(x, 0.01x); inner loop pinned to 4 VOP3P insts via asm.
#define R_HC 64   // h2 pairs per block (=128 h), 4 splits -> 512 blocks

__global__ __launch_bounds__(256) void reduce_b(
    const uint32_t* __restrict__ htT2, const uint32_t* __restrict__ hoT2,
    const float* __restrict__ W2, float* __restrict__ part)
{
    __shared__ __align__(16) uint32_t ht_s[R_HC * 64];  // [h2][t]
    __shared__ __align__(16) uint32_t ho_s[R_HC * 64];  // [h2][o]
    __shared__ uint32_t w2s[R_HC];

    const int tid = threadIdx.x;
    const int t0 = blockIdx.x * 64;
    const int o0 = blockIdx.y * 64;
    const int h2b = blockIdx.z * R_HC;

    if (tid < R_HC)
        w2s[tid] = pack2(W2[(h2b + tid) * 2], W2[(h2b + tid) * 2 + 1]);

#pragma unroll
    for (int r = 0; r < 4; ++r) {
        const int c = tid + r * 256;
        const int row = c >> 4;
        const int c4 = (c & 15) * 4;
        *reinterpret_cast<uint4*>(&ht_s[row * 64 + c4]) =
            *reinterpret_cast<const uint4*>(&htT2[(size_t)(h2b + row) * T_DIM + t0 + c4]);
        *reinterpret_cast<uint4*>(&ho_s[row * 64 + c4]) =
            *reinterpret_cast<const uint4*>(&hoT2[(size_t)(h2b + row) * O_DIM + o0 + c4]);
    }
    __syncthreads();

    const int tx = tid & 15;   // o dir, 4 each
    const int ty = tid >> 4;   // t dir, 4 each

    const uint32_t c001 = pack2(0.01f, 0.01f);   // hoisted VGPR constant

    float acc[4][4] = {};

#pragma unroll 4
    for (int h2 = 0; h2 < R_HC; ++h2) {
        const uint32_t w = w2s[h2];
        uint4 a = *reinterpret_cast<const uint4*>(&ht_s[h2 * 64 + ty * 4]);
        uint4 b = *reinterpret_cast<const uint4*>(&ho_s[h2 * 64 + tx * 4]);
        uint32_t av[4] = {a.x, a.y, a.z, a.w};
        uint32_t bv[4] = {b.x, b.y, b.z, b.w};
#pragma unroll
        for (int i = 0; i < 4; ++i)
#pragma unroll
            for (int j = 0; j < 4; ++j) {
                uint32_t s  = pk_add(av[i], bv[j]);   // v_pk_add_f16
                uint32_t s2 = pk_mul(s, c001);        // v_pk_mul_f16
                uint32_t l  = pk_max(s, s2);          // v_pk_max_f16
                acc[i][j]   = dot2(l, w, acc[i][j]);  // v_dot2_f32_f16
            }
    }

    float* p = part + (size_t)blockIdx.z * T_DIM * O_DIM;
#pragma unroll
    for (int i = 0; i < 4; ++i) {
        float4 v = make_float4(acc[i][0], acc[i][1], acc[i][2], acc[i][3]);
        *reinterpret_cast<float4*>(
            &p[(size_t)(t0 + ty * 4 + i) * O_DIM + o0 + tx * 4]) = v;
    }
}

// ---------------- Kernel C: combine ----------------------------------------
// out = b2 + sum_{hs=0..3} part[hs]
__global__ __launch_bounds__(256) void combine(
    const float* __restrict__ part, const float* __restrict__ b2,
    float* __restrict__ out)
{
    const float bb = b2[0];
    const int Q = T_DIM * O_DIM / 4;
#pragma unroll
    for (int r = 0; r < 2; ++r) {
        const int idx = blockIdx.x * 512 + r * 256 + threadIdx.x;
        const float4* p = reinterpret_cast<const float4*>(part);
        float4 s0 = p[idx];
        float4 s1 = p[idx + Q];
        float4 s2 = p[idx + 2 * Q];
        float4 s3 = p[idx + 3 * Q];
        float4 o;
        o.x = bb + (s0.x + s1.x) + (s2.x + s3.x);
        o.y = bb + (s0.y + s1.y) + (s2.y + s3.y);
        o.z = bb + (s0.z + s1.z) + (s2.z + s3.z);
        o.w = bb + (s0.w + s1.w) + (s2.w + s3.w);
        reinterpret_cast<float4*>(out)[idx] = o;
    }
}

extern "C" void kernel_launch(void* const* d_in, const int* in_sizes, int n_in,
                              void* d_out, int out_size, void* d_ws, size_t ws_size,
                              hipStream_t stream) {
    const float* z_t = (const float*)d_in[0];
    const float* z_o = (const float*)d_in[1];
    const float* W1  = (const float*)d_in[2];
    const float* b1  = (const float*)d_in[3];
    const float* W2  = (const float*)d_in[4];
    const float* b2  = (const float*)d_in[5];
    float* out = (float*)d_out;

    // ws layout: htT2 1MB | hoT2 0.5MB | part 8MB @ 2MB
    char* wsb = (char*)d_ws;
    uint32_t* htT2 = (uint32_t*)(wsb);
    uint32_t* hoT2 = (uint32_t*)(wsb + (1u << 20));
    float* part    = (float*)(wsb + 0x200000);

    dim3 gridA((T_DIM + O_DIM) / 64, H_DIM / 64);       // (24, 8)
    gemm_a<<<gridA, 256, 0, stream>>>(z_t, z_o, W1, b1, htT2, hoT2);

    dim3 gridB(T_DIM / 64, O_DIM / 64, H2_DIM / R_HC);  // (16, 8, 4)
    reduce_b<<<gridB, 256, 0, stream>>>(htT2, hoT2, W2, part);

    combine<<<T_DIM * O_DIM / (4 * 512), 256, 0, stream>>>(part, b2, out);
}